// Round 14
// baseline (138.790 us; speedup 1.0000x reference)
//
#include <hip/hip_runtime.h>
#include <math.h>

#define NTHR 256
#define WAVES_PER_BLOCK 4
#define NBLOCKS 2048

typedef __attribute__((ext_vector_type(8))) _Float16 f16x8;   // MFMA A/B frag (4 VGPRs)
typedef __attribute__((ext_vector_type(2))) _Float16 half2v;
typedef __attribute__((ext_vector_type(4))) float f32x4;      // MFMA C/D frag + packed math
typedef __attribute__((ext_vector_type(4))) unsigned uint4v;

#define CEXP 28.85390082f     // 20 * log2(e)
#define KLOG 0.03465735903f   // ln(2) / 20

#define EXP2F(v) __builtin_amdgcn_exp2f(v)
#define LOG2F(v) __builtin_amdgcn_logf(v)

static __device__ __forceinline__ f32x4 splat4(float v) { return (f32x4){v, v, v, v}; }

// Vectorized softplus(beta=20) + derivative (packed fp32 math, scalar trans).
static __device__ __forceinline__ void act_hs4(f32x4 z, f32x4& h, f32x4& s) {
    f32x4 az = __builtin_elementwise_abs(splat4(CEXP) * z);
    f32x4 e;
    #pragma unroll
    for (int i = 0; i < 4; ++i) e[i] = EXP2F(-az[i]);
    f32x4 p = splat4(1.0f) + e;
    f32x4 l;
    #pragma unroll
    for (int i = 0; i < 4; ++i) l[i] = LOG2F(p[i]);
    f32x4 zp = __builtin_elementwise_max(z, splat4(0.0f));
    f32x4 q  = __builtin_elementwise_fma(splat4(-CEXP), zp, -l);
    f32x4 t;
    #pragma unroll
    for (int i = 0; i < 4; ++i) t[i] = EXP2F(q[i]);
    s = splat4(1.0f) - t;
    h = __builtin_elementwise_fma(splat4(KLOG), l, zp);
}

static __device__ __forceinline__ f32x4 sigmoid4(f32x4 z) {
    f32x4 cz = splat4(-CEXP) * z;
    f32x4 e;
    #pragma unroll
    for (int i = 0; i < 4; ++i) e[i] = EXP2F(cz[i]);
    f32x4 p = splat4(1.0f) + e;
    f32x4 r;
    #pragma unroll
    for (int i = 0; i < 4; ++i) r[i] = __builtin_amdgcn_rcpf(p[i]);
    return r;
}

static __device__ __forceinline__ unsigned pk(float a, float b) {
    return __builtin_bit_cast(unsigned, __builtin_amdgcn_cvt_pkrtz(a, b));
}

static __device__ __forceinline__ f16x8 pack8v(const f32x4& a, const f32x4& b) {
    uint4v u = {pk(a[0], a[1]), pk(a[2], a[3]), pk(b[0], b[1]), pk(b[2], b[3])};
    return __builtin_bit_cast(f16x8, u);
}
static __device__ __forceinline__ void fsplit8v(const f32x4& a, const f32x4& b,
                                                f16x8& hi, f16x8& lo) {
    unsigned h[4], l[4];
    #pragma unroll
    for (int p2 = 0; p2 < 2; ++p2) {
        float u0 = a[2 * p2], u1 = a[2 * p2 + 1];
        unsigned hp = pk(u0, u1);
        half2v hh = __builtin_bit_cast(half2v, hp);
        h[p2] = hp;
        l[p2] = pk(u0 - (float)hh[0], u1 - (float)hh[1]);
        float w0 = b[2 * p2], w1 = b[2 * p2 + 1];
        unsigned hq = pk(w0, w1);
        half2v hh2 = __builtin_bit_cast(half2v, hq);
        h[2 + p2] = hq;
        l[2 + p2] = pk(w0 - (float)hh2[0], w1 - (float)hh2[1]);
    }
    hi = __builtin_bit_cast(f16x8, (uint4v){h[0], h[1], h[2], h[3]});
    lo = __builtin_bit_cast(f16x8, (uint4v){l[0], l[1], l[2], l[3]});
}

static __device__ __forceinline__ f32x4 mfma2f(f16x8 w, f16x8 bh, f16x8 bl, f32x4 c) {
    c = __builtin_amdgcn_mfma_f32_16x16x32_f16(w, bh, c, 0, 0, 0);
    c = __builtin_amdgcn_mfma_f32_16x16x32_f16(w, bl, c, 0, 0, 0);
    return c;
}
static __device__ __forceinline__ f32x4 mfma1t(f16x8 w, f16x8 b, f32x4 c) {
    return __builtin_amdgcn_mfma_f32_16x16x32_f16(w, b, c, 0, 0, 0);
}

__global__ void __launch_bounds__(NTHR)
presdiv_kernel(const float* __restrict__ x,
               const float* __restrict__ W1, const float* __restrict__ b1,
               const float* __restrict__ W2, const float* __restrict__ b2,
               const float* __restrict__ W3, const float* __restrict__ b3,
               const float* __restrict__ W4,
               float* __restrict__ out, int N)
{
    const int lane = threadIdx.x & 63;
    const int wid  = threadIdx.x >> 6;
    const int n16  = lane & 15;
    const int g    = lane >> 4;

    // ---- persistent weights (shared by both interleaved tiles) ----
    f16x8 w2[2], w3[2];
    #pragma unroll
    for (int h = 0; h < 2; ++h) {
        #pragma unroll
        for (int j = 0; j < 8; ++j) {
            const int k2 = g * 8 + j;
            w2[h][j] = (_Float16)W2[k2 * 32 + 16 * h + n16];
            const int k3 = (j < 4) ? (4 * g + j) : (16 + 4 * g + (j - 4));
            w3[h][j] = (_Float16)W3[k3 * 32 + 16 * h + n16];
        }
    }
    f32x4 w1v[3][2], bb1v[2];
    #pragma unroll
    for (int c = 0; c < 2; ++c)
        #pragma unroll
        for (int i = 0; i < 4; ++i) {
            const int j = 4 * c + i;
            bb1v[c][i] = b1[g * 8 + j];
            #pragma unroll
            for (int d = 0; d < 3; ++d) w1v[d][c][i] = W1[d * 32 + g * 8 + j];
        }
    f32x4 bb2v[2], bb3v[2], w4c[2][3];
    #pragma unroll
    for (int h = 0; h < 2; ++h)
        #pragma unroll
        for (int r = 0; r < 4; ++r) {
            const int row = 16 * h + 4 * g + r;
            bb2v[h][r] = b2[row];
            bb3v[h][r] = b3[row];
            #pragma unroll
            for (int k = 0; k < 3; ++k) w4c[h][k][r] = W4[row * 3 + k];
        }

    const int ntiles = (N + 15) >> 4;
    const int npairs = (ntiles + 1) >> 1;
    const int nwaves = NBLOCKS * WAVES_PER_BLOCK;
    const f32x4 vzero = {0.f, 0.f, 0.f, 0.f};

    for (int pair = blockIdx.x * WAVES_PER_BLOCK + wid; pair < npairs; pair += nwaves) {
        // two adjacent tiles -> 32 consecutive samples, coalesced x loads
        int ss[2];
        f32x4 X0[2], X1[2], X2[2];
        #pragma unroll
        for (int t = 0; t < 2; ++t) {
            int s = pair * 32 + 16 * t + n16;
            if (s >= N) s = N - 1;
            ss[t] = s;
            X0[t] = splat4(x[3 * s + 0]);
            X1[t] = splat4(x[3 * s + 1]);
            X2[t] = splat4(x[3 * s + 2]);
        }

        // ---- layer 1, both tiles ----
        f32x4 vFv[2][2], v0v[2][2], v1v[2][2], v2v[2][2];
        #pragma unroll
        for (int t = 0; t < 2; ++t)
            #pragma unroll
            for (int c = 0; c < 2; ++c) {
                f32x4 z = __builtin_elementwise_fma(X0[t], w1v[0][c], bb1v[c]);
                z = __builtin_elementwise_fma(X1[t], w1v[1][c], z);
                z = __builtin_elementwise_fma(X2[t], w1v[2][c], z);
                f32x4 hv, sv;
                act_hs4(z, hv, sv);
                vFv[t][c] = hv;
                v0v[t][c] = sv * w1v[0][c];
                v1v[t][c] = sv * w1v[1][c];
                v2v[t][c] = sv * w1v[2][c];
            }

        // ---- layer 2, both tiles interleaved ----
        f32x4 aF[2][2], a0[2][2], a1[2][2], a2[2][2];
        #pragma unroll
        for (int t = 0; t < 2; ++t) {
            aF[t][0] = bb2v[0]; aF[t][1] = bb2v[1];
            a0[t][0] = a0[t][1] = a1[t][0] = a1[t][1] = a2[t][0] = a2[t][1] = vzero;
        }
        #pragma unroll
        for (int t = 0; t < 2; ++t) {
            f16x8 bh, bl;
            fsplit8v(vFv[t][0], vFv[t][1], bh, bl);
            aF[t][0] = mfma2f(w2[0], bh, bl, aF[t][0]);
            aF[t][1] = mfma2f(w2[1], bh, bl, aF[t][1]);
            f16x8 tb = pack8v(v0v[t][0], v0v[t][1]);
            a0[t][0] = mfma1t(w2[0], tb, a0[t][0]);
            a0[t][1] = mfma1t(w2[1], tb, a0[t][1]);
            tb = pack8v(v1v[t][0], v1v[t][1]);
            a1[t][0] = mfma1t(w2[0], tb, a1[t][0]);
            a1[t][1] = mfma1t(w2[1], tb, a1[t][1]);
            tb = pack8v(v2v[t][0], v2v[t][1]);
            a2[t][0] = mfma1t(w2[0], tb, a2[t][0]);
            a2[t][1] = mfma1t(w2[1], tb, a2[t][1]);
        }

        // ---- boundary act, both tiles ----
        #pragma unroll
        for (int t = 0; t < 2; ++t)
            #pragma unroll
            for (int h = 0; h < 2; ++h) {
                f32x4 hv, sv;
                act_hs4(aF[t][h], hv, sv);
                aF[t][h] = hv;
                a0[t][h] *= sv;
                a1[t][h] *= sv;
                a2[t][h] *= sv;
            }

        // ---- layer 3, both tiles ----
        f32x4 zF[2][2], u0[2][2], u1[2][2], u2[2][2];
        #pragma unroll
        for (int t = 0; t < 2; ++t) {
            zF[t][0] = bb3v[0]; zF[t][1] = bb3v[1];
            u0[t][0] = u0[t][1] = u1[t][0] = u1[t][1] = u2[t][0] = u2[t][1] = vzero;
        }
        #pragma unroll
        for (int t = 0; t < 2; ++t) {
            f16x8 bh, bl;
            fsplit8v(aF[t][0], aF[t][1], bh, bl);
            zF[t][0] = mfma2f(w3[0], bh, bl, zF[t][0]);
            zF[t][1] = mfma2f(w3[1], bh, bl, zF[t][1]);
            f16x8 tb = pack8v(a0[t][0], a0[t][1]);
            u0[t][0] = mfma1t(w3[0], tb, u0[t][0]);
            u0[t][1] = mfma1t(w3[1], tb, u0[t][1]);
            tb = pack8v(a1[t][0], a1[t][1]);
            u1[t][0] = mfma1t(w3[0], tb, u1[t][0]);
            u1[t][1] = mfma1t(w3[1], tb, u1[t][1]);
            tb = pack8v(a2[t][0], a2[t][1]);
            u2[t][0] = mfma1t(w3[0], tb, u2[t][0]);
            u2[t][1] = mfma1t(w3[1], tb, u2[t][1]);
        }

        // ---- layer 4 + trace combine + reduce + store, both tiles ----
        #pragma unroll
        for (int t = 0; t < 2; ++t) {
            f32x4 O0 = vzero, O1 = vzero, O2 = vzero;
            #pragma unroll
            for (int h = 0; h < 2; ++h) {
                const f32x4 S  = sigmoid4(zF[t][h]);
                const f32x4 T0 = S * u0[t][h];
                const f32x4 T1 = S * u1[t][h];
                const f32x4 T2 = S * u2[t][h];
                O0 = __builtin_elementwise_fma(T1, w4c[h][0],
                     __builtin_elementwise_fma(T2, w4c[h][1], O0));
                O1 = __builtin_elementwise_fma(-T0, w4c[h][0],
                     __builtin_elementwise_fma(T2, w4c[h][2], O1));
                O2 = __builtin_elementwise_fma(-T0, w4c[h][1],
                     __builtin_elementwise_fma(-T1, w4c[h][2], O2));
            }
            float o0 = (O0[0] + O0[1]) + (O0[2] + O0[3]);
            float o1 = (O1[0] + O1[1]) + (O1[2] + O1[3]);
            float o2 = (O2[0] + O2[1]) + (O2[2] + O2[3]);

            o0 += __shfl_xor(o0, 16); o0 += __shfl_xor(o0, 32);
            o1 += __shfl_xor(o1, 16); o1 += __shfl_xor(o1, 32);
            o2 += __shfl_xor(o2, 16); o2 += __shfl_xor(o2, 32);

            if (g == 0) {
                out[3 * ss[t] + 0] = o0;
                out[3 * ss[t] + 1] = o1;
                out[3 * ss[t] + 2] = o2;
            }
        }
    }
}

extern "C" void kernel_launch(void* const* d_in, const int* in_sizes, int n_in,
                              void* d_out, int out_size, void* d_ws, size_t ws_size,
                              hipStream_t stream)
{
    const float* x  = (const float*)d_in[0];
    const float* W1 = (const float*)d_in[1];
    const float* b1 = (const float*)d_in[2];
    const float* W2 = (const float*)d_in[3];
    const float* b2 = (const float*)d_in[4];
    const float* W3 = (const float*)d_in[5];
    const float* b3 = (const float*)d_in[6];
    const float* W4 = (const float*)d_in[7];
    // d_in[8] = b4 unused: constant offset cancels in the Jacobian.
    float* out = (float*)d_out;

    const int N = in_sizes[0] / 3;
    presdiv_kernel<<<NBLOCKS, NTHR, 0, stream>>>(x, W1, b1, W2, b2, W3, b3, W4, out, N);
}